// Round 7
// baseline (109.468 us; speedup 1.0000x reference)
//
#include <hip/hip_runtime.h>
#include <math.h>

#define NBATCH 64
#define NGT    40
#define HW0    25600
#define HW1    6400
#define HW2    1600
#define NBLK   (NBATCH*3)    // 192 fused blocks, one per (b,sc)
#define MAXE   400
#define SENT   0xFFFFFFFFFFFFFFFFull
#define FEPS   1e-7f

__device__ __forceinline__ float frcp(float x){ return __builtin_amdgcn_rcpf(x); }
__device__ __forceinline__ float fsigm(float x){ return frcp(1.0f + __expf(-x)); }

// focal loss at z=0 and general z — identical instruction sequences so the
// dense z=0 term cancels (to fp rounding) against the owner-side subtraction.
__device__ __forceinline__ float focal0(float x){
  float e = __expf(-fabsf(x));
  float ce = fmaxf(x,0.0f) + __logf(1.0f+e);
  float prob = fsigm(x);
  return 0.75f*prob*prob*ce;
}
__device__ __forceinline__ float focalz(float x, float z){
  float e = __expf(-fabsf(x));
  float ce = fmaxf(x,0.0f) - x*z + __logf(1.0f+e);
  float prob = fsigm(x);
  float p_t = prob*z + (1.0f-prob)*(1.0f-z);
  float a_t = 0.25f*z + 0.75f*(1.0f-z);
  float om = 1.0f-p_t;
  return a_t*om*om*ce;
}

__device__ __forceinline__ unsigned long long shflx64(unsigned long long v, int m){
  int lo = __shfl_xor((int)(unsigned)(v & 0xFFFFFFFFull), m, 64);
  int hi = __shfl_xor((int)(unsigned)(v >> 32), m, 64);
  return (((unsigned long long)(unsigned)hi) << 32) | (unsigned)lo;
}
__device__ __forceinline__ float wredf(float v){
  #pragma unroll
  for (int o=32;o;o>>=1) v += __shfl_xor(v,o,64);
  return v;
}
__device__ __forceinline__ int wredi(int v){
  #pragma unroll
  for (int o=32;o;o>>=1) v += __shfl_xor(v,o,64);
  return v;
}
__device__ __forceinline__ unsigned long long wredmin64(unsigned long long v){
  #pragma unroll
  for (int o=32;o;o>>=1){ unsigned long long w = shflx64(v,o); v = (w<v)?w:v; }
  return v;
}

__device__ __forceinline__ float iou_of_cell_f(const float* __restrict__ P, int HW, int cell,
                                               int W, float s,
                                               float bx1, float by1, float bx2, float by2, float ab){
  int gy = cell / W;
  int gx = cell - gy*W;
  float gxf=(float)gx, gyf=(float)gy;
  float q1 = P[HW+cell], q2=P[2*HW+cell], q3=P[3*HW+cell], q4=P[4*HW+cell];
  float pcx = (fsigm(q1)+gxf)*s;
  float pcy = (fsigm(q2)+gyf)*s;
  float pw = __expf(fminf(fmaxf(q3,-5.0f),5.0f))*s;
  float ph = __expf(fminf(fmaxf(q4,-5.0f),5.0f))*s;
  float ax1=pcx-pw*0.5f, ay1=pcy-ph*0.5f, ax2=pcx+pw*0.5f, ay2=pcy+ph*0.5f;
  float ltx=fmaxf(ax1,bx1), lty=fmaxf(ay1,by1);
  float rbx=fminf(ax2,bx2), rby=fminf(ay2,by2);
  float iw=fmaxf(rbx-ltx,0.0f), ih=fmaxf(rby-lty,0.0f);
  float inter=iw*ih;
  float aa=(ax2-ax1)*(ay2-ay1);
  return inter*frcp(aa+ab-inter+FEPS);
}

// One block per (b, sc). Phase A: 16 waves scan the 40 GT tasks, selections
// go straight into LDS (no global interface). Phase B: sparse winner resolve
// + dense z=0 focal stream + CIoU/foot -> one partial float per block.
__global__ __launch_bounds__(1024) void k_fused(
    const float* __restrict__ p0, const float* __restrict__ p1,
    const float* __restrict__ p2, const float* __restrict__ tg,
    float* __restrict__ partials)
{
  __shared__ int   s_pack[MAXE];   // (cell<<6)|g
  __shared__ float s_biou[MAXE];
  __shared__ int   s_cnt;
  __shared__ float red[4][16];

  int u = blockIdx.x;        // 0..191 == b*3+sc
  int b = u / 3, sc = u - b*3;
  int W, HW; float s; const float* P;
  if (sc==0)      { W=160; HW=HW0; s=8.0f/1280.0f;  P=p0; }
  else if (sc==1) { W=80;  HW=HW1; s=16.0f/1280.0f; P=p1; }
  else            { W=40;  HW=HW2; s=32.0f/1280.0f; P=p2; }
  P += (size_t)b*7*HW;
  float inv_s = 1280.0f/(float)((sc==0)?8:(sc==1)?16:32);

  if (threadIdx.x == 0) s_cnt = 0;
  __syncthreads();

  int lane = threadIdx.x & 63;
  int wv   = threadIdx.x >> 6;    // 0..15

  // ---- phase A: per-wave GT tasks ----
  for (int g = wv; g < NGT; g += 16){
    const float* tp = tg + (b*NGT + g)*7;
    float cls = tp[0], cx = tp[1], cy = tp[2], w = tp[3], h = tp[4];
    float sz = fmaxf(w,h)*1280.0f;
    bool valid = (cls == 0.0f);
    if (sc==0)      valid = valid && (sz < 128.0f);
    else if (sc==1) valid = valid && (sz >= 48.0f) && (sz < 288.0f);
    else            valid = valid && (sz >= 128.0f);
    if (!valid) continue;

    float cxg = cx*inv_s, cyg = cy*inv_s;
    float bx1 = cx - w*0.5f, bx2 = cx + w*0.5f;
    float by1 = cy - h*0.5f, by2 = cy + h*0.5f;
    float ab  = (bx2-bx1)*(by2-by1);
    float bxl = bx1*inv_s, bxr = bx2*inv_s, byt = by1*inv_s, byb = by2*inv_s;

    // bounding rect of (in_center | in_box), +1 margin; exact predicates inside
    int x0 = max(0,   (int)floorf(fminf(cxg-2.5f, bxl)) - 1);
    int x1 = min(W-1, (int)floorf(fmaxf(cxg+2.5f, bxr)) + 1);
    int y0 = max(0,   (int)floorf(fminf(cyg-2.5f, byt)) - 1);
    int y1 = min(W-1, (int)floorf(fmaxf(cyg+2.5f, byb)) + 1);
    int rw = x1-x0+1, rh = y1-y0+1;
    int rn = rw*rh;

    unsigned long long t[10];
    #pragma unroll
    for (int j=0;j<10;++j) t[j]=SENT;
    int ncand = 0; float iousum = 0.0f;
    unsigned long long dmin = SENT;

    int rx = lane % rw, ry = lane / rw;
    int stepy = 64 / rw, stepx = 64 % rw;
    for (int r = lane; r < rn; r += 64){
      float gxf = (float)(x0+rx), gyf = (float)(y0+ry);
      int cell = (y0+ry)*W + (x0+rx);
      float q1 = P[HW+cell], q2 = P[2*HW+cell], q3 = P[3*HW+cell], q4 = P[4*HW+cell];
      float pcx = (fsigm(q1)+gxf)*s;
      float pcy = (fsigm(q2)+gyf)*s;
      float pw = __expf(fminf(fmaxf(q3,-5.0f),5.0f))*s;
      float ph = __expf(fminf(fmaxf(q4,-5.0f),5.0f))*s;
      float ax1 = pcx-pw*0.5f, ay1 = pcy-ph*0.5f, ax2 = pcx+pw*0.5f, ay2 = pcy+ph*0.5f;
      float ltx = fmaxf(ax1,bx1), lty = fmaxf(ay1,by1);
      float rbx = fminf(ax2,bx2), rby = fminf(ay2,by2);
      float iw = fmaxf(rbx-ltx,0.0f), ih = fmaxf(rby-lty,0.0f);
      float inter = iw*ih;
      float aa = (ax2-ax1)*(ay2-ay1);
      float iou = inter * frcp(aa+ab-inter+FEPS);
      bool ic = (fabsf(gxf-cxg)<2.5f) && (fabsf(gyf-cyg)<2.5f);
      bool ib = (gxf>=bxl)&&(gxf<bxr)&&(gyf>=byt)&&(gyf<byb);
      float dx = gxf-cxg, dy = gyf-cyg;
      float dist = dx*dx+dy*dy;
      unsigned long long dk = (((unsigned long long)__float_as_uint(dist))<<32)|(unsigned)cell;
      dmin = (dk<dmin)?dk:dmin;
      if (ic|ib){
        ncand += 1; iousum += iou;
        float q0 = P[cell];
        // monotone-equivalent cost key: (1+e^-q0)/(iou+eps)^3 — skips 2 logs
        float ti = iou + FEPS;
        float ratio = (1.0f + __expf(-q0)) * frcp(ti*ti*ti);
        unsigned long long pk = (((unsigned long long)__float_as_uint(ratio))<<32)|(unsigned)cell;
        if (pk < t[9]){
          t[9] = pk;
          #pragma unroll
          for (int j=9;j>0;--j){ if (t[j]<t[j-1]){ unsigned long long tmp=t[j]; t[j]=t[j-1]; t[j-1]=tmp; } }
        }
      }
      rx += stepx; ry += stepy;
      if (rx >= rw){ rx -= rw; ry += 1; }
    }

    int NC = wredi(ncand);        // butterfly: all lanes get results
    float IS = wredf(iousum);
    dmin = wredmin64(dmin);

    int npos;
    if (NC==0) npos = 1;           // fallback (never fires w/ this data)
    else {
      int ub = NC < 10 ? NC : 10;
      int v = (int)floorf(IS);
      v = v < 1 ? 1 : v;
      npos = v > ub ? ub : v;
    }
    int idx = 0;
    if (lane==0) idx = atomicAdd(&s_cnt, npos);

    int cell0;
    if (NC==0){
      cell0 = (int)(unsigned)dmin;
      if (lane==0) s_pack[idx] = (cell0<<6) | g;
    } else {
      int ptr = 0; cell0 = 0;
      for (int rd=0; rd<npos; ++rd){
        unsigned long long head = SENT;
        #pragma unroll
        for (int j=0;j<10;++j) head = (ptr==j)? t[j] : head;
        unsigned long long m = wredmin64(head);
        if (rd==0) cell0 = (int)(unsigned)m;
        if (lane==0) s_pack[idx+rd] = (((int)(unsigned)m)<<6) | g;
        if (head==m && m!=SENT) ptr += 1;
      }
    }
    if (lane==0){
      float biou = iou_of_cell_f(P, HW, cell0, W, s, bx1, by1, bx2, by2, ab);
      for (int sl=0; sl<npos; ++sl) s_biou[idx+sl] = biou;
    }
  }
  __syncthreads();
  int E = s_cnt;

  // ---- phase B ----
  float osum = 0.0f, np = 0.0f, bsum = 0.0f, fsum = 0.0f;

  // dense z=0 focal over the whole obj plane (coalesced float4)
  {
    const float4* P4 = (const float4*)P;
    int n4 = HW >> 2;
    for (int i = threadIdx.x; i < n4; i += 1024){
      float4 x4 = P4[i];
      osum += focal0(x4.x) + focal0(x4.y) + focal0(x4.z) + focal0(x4.w);
    }
  }

  // sparse: resolve winner (max g) and obj (max biou) per selected cell
  if (threadIdx.x < E){
    int myp = s_pack[threadIdx.x];
    int mycell = myp >> 6;
    int pm = myp; float bm = s_biou[threadIdx.x];
    for (int j = 0; j < E; ++j){
      int p = s_pack[j];
      if ((p>>6) == mycell){
        pm = max(pm, p);
        bm = fmaxf(bm, s_biou[j]);
      }
    }
    if (pm == myp){            // this entry owns the cell (max g, unique)
      np = 1.0f;
      int wg = myp & 63;
      float z = bm;
      int i = mycell;
      float x = P[i];
      osum += focalz(x, z) - focal0(x);    // correct the dense z=0 term
      const float* tpb = tg + (b*NGT + wg)*7;
      float cx=tpb[1], cy=tpb[2], w=tpb[3], h=tpb[4], fx=tpb[5], fy=tpb[6];
      int gyi = i / W;
      float gxf = (float)(i - gyi*W), gyf = (float)gyi;
      float pcx = (fsigm(P[HW+i])+gxf)*s;
      float pcy = (fsigm(P[2*HW+i])+gyf)*s;
      float pw = __expf(fminf(fmaxf(P[3*HW+i],-5.0f),5.0f))*s;
      float ph = __expf(fminf(fmaxf(P[4*HW+i],-5.0f),5.0f))*s;
      float tw = w + FEPS*s, th = h + FEPS*s;   // exp(log(w/s+eps))*s
      float px1=pcx-pw*0.5f, py1=pcy-ph*0.5f, px2=pcx+pw*0.5f, py2=pcy+ph*0.5f;
      float tx1=cx-tw*0.5f, ty1=cy-th*0.5f, tx2=cx+tw*0.5f, ty2=cy+th*0.5f;
      float iw = fmaxf(fminf(px2,tx2)-fmaxf(px1,tx1),0.0f);
      float ih = fmaxf(fminf(py2,ty2)-fmaxf(py1,ty1),0.0f);
      float inter = iw*ih;
      float uni = pw*ph + tw*th - inter + FEPS;
      float iou = inter/uni;
      float rho2 = (pcx-cx)*(pcx-cx)+(pcy-cy)*(pcy-cy);
      float cw = fmaxf(px2,tx2)-fminf(px1,tx1);
      float ch = fmaxf(py2,ty2)-fminf(py1,ty1);
      float c2 = cw*cw+ch*ch+FEPS;
      float da = atanf(tw/(th+FEPS)) - atanf(pw/(ph+FEPS));
      float v = (4.0f/(float)(M_PI*M_PI))*da*da;
      float alpha = v/(1.0f-iou+v+FEPS);
      float ciou = iou - rho2/c2 - alpha*v;
      bsum = 1.0f - ciou;
      float pf1 = fsigm(P[5*HW+i]);
      float pf2 = fsigm(P[6*HW+i]);
      float d1 = fabsf(pf1-fx), d2 = fabsf(pf2-fy);
      fsum = (d1<1.0f? 0.5f*d1*d1 : d1-0.5f) + (d2<1.0f? 0.5f*d2*d2 : d2-0.5f);
    }
  }

  // block reduction (16 waves) -> one partial float
  osum = wredf(osum); np = wredf(np); bsum = wredf(bsum); fsum = wredf(fsum);
  if (lane==0){ red[0][wv]=osum; red[1][wv]=np; red[2][wv]=bsum; red[3][wv]=fsum; }
  __syncthreads();
  if (threadIdx.x==0){
    float a0=0,a1=0,a2=0,a3=0;
    #pragma unroll
    for (int j=0;j<16;++j){ a0+=red[0][j]; a1+=red[1][j]; a2+=red[2][j]; a3+=red[3][j]; }
    float hw = (float)HW;
    float npz = fmaxf(a1, 1.0f);
    partials[u] = a0/hw + 5.0f*a2/npz + a3/npz;
  }
}

// deterministic final reduce: 192 partials -> out[0]
__global__ void k_final(const float* __restrict__ partials, float* __restrict__ out){
  int t = threadIdx.x;
  float c = (t < NBLK) ? partials[t] : 0.0f;
  c = wredf(c);
  __shared__ float sh[4];
  if ((t & 63) == 0) sh[t >> 6] = c;
  __syncthreads();
  if (t == 0) out[0] = (sh[0]+sh[1]+sh[2]+sh[3])*(1.0f/64.0f);
}

extern "C" void kernel_launch(void* const* d_in, const int* in_sizes, int n_in,
                              void* d_out, int out_size, void* d_ws, size_t ws_size,
                              hipStream_t stream) {
  (void)in_sizes; (void)n_in; (void)out_size; (void)ws_size;
  const float* p0 = (const float*)d_in[0];
  const float* p1 = (const float*)d_in[1];
  const float* p2 = (const float*)d_in[2];
  const float* tg = (const float*)d_in[3];

  float* partials = (float*)d_ws;   // NBLK floats (write-only; poison OK)
  float* out      = (float*)d_out;

  k_fused<<<NBLK, 1024, 0, stream>>>(p0, p1, p2, tg, partials);
  k_final<<<1, 256, 0, stream>>>(partials, out);
}

// Round 8
// 106.711 us; speedup vs baseline: 1.0258x; 1.0258x over previous
//
#include <hip/hip_runtime.h>
#include <math.h>

#define NBATCH 64
#define NGT    40
#define HW0    25600
#define HW1    6400
#define HW2    1600
#define NTASK  (NBATCH*3*NGT)   // 7680
#define NABLK  (NTASK/4)        // 1920 assign blocks, 10 per (b,sc)
#define MAXE   400
#define SENT   0xFFFFFFFFFFFFFFFFull
#define FEPS   1e-7f

__device__ __forceinline__ float frcp(float x){ return __builtin_amdgcn_rcpf(x); }
__device__ __forceinline__ float fsigm(float x){ return frcp(1.0f + __expf(-x)); }

// focal loss at z=0 and general z — identical instruction sequences so the
// dense term cancels exactly against the owner-side subtraction.
__device__ __forceinline__ float focal0(float x){
  float e = __expf(-fabsf(x));
  float ce = fmaxf(x,0.0f) + __logf(1.0f+e);
  float prob = fsigm(x);
  return 0.75f*prob*prob*ce;
}
__device__ __forceinline__ float focalz(float x, float z){
  float e = __expf(-fabsf(x));
  float ce = fmaxf(x,0.0f) - x*z + __logf(1.0f+e);
  float prob = fsigm(x);
  float p_t = prob*z + (1.0f-prob)*(1.0f-z);
  float a_t = 0.25f*z + 0.75f*(1.0f-z);
  float om = 1.0f-p_t;
  return a_t*om*om*ce;
}

__device__ __forceinline__ unsigned long long shflx64(unsigned long long v, int m){
  int lo = __shfl_xor((int)(unsigned)(v & 0xFFFFFFFFull), m, 64);
  int hi = __shfl_xor((int)(unsigned)(v >> 32), m, 64);
  return (((unsigned long long)(unsigned)hi) << 32) | (unsigned)lo;
}
__device__ __forceinline__ float wredf(float v){
  #pragma unroll
  for (int o=32;o;o>>=1) v += __shfl_xor(v,o,64);
  return v;
}
__device__ __forceinline__ int wredi(int v){
  #pragma unroll
  for (int o=32;o;o>>=1) v += __shfl_xor(v,o,64);
  return v;
}
__device__ __forceinline__ unsigned long long wredmin64(unsigned long long v){
  #pragma unroll
  for (int o=32;o;o>>=1){ unsigned long long w = shflx64(v,o); v = (w<v)?w:v; }
  return v;
}

__device__ __forceinline__ float iou_of_cell_f(const float* __restrict__ P, int HW, int cell,
                                               int W, float s,
                                               float bx1, float by1, float bx2, float by2, float ab){
  int gy = cell / W;
  int gx = cell - gy*W;
  float gxf=(float)gx, gyf=(float)gy;
  float q1 = P[HW+cell], q2=P[2*HW+cell], q3=P[3*HW+cell], q4=P[4*HW+cell];
  float pcx = (fsigm(q1)+gxf)*s;
  float pcy = (fsigm(q2)+gyf)*s;
  float pw = __expf(fminf(fmaxf(q3,-5.0f),5.0f))*s;
  float ph = __expf(fminf(fmaxf(q4,-5.0f),5.0f))*s;
  float ax1=pcx-pw*0.5f, ay1=pcy-ph*0.5f, ax2=pcx+pw*0.5f, ay2=pcy+ph*0.5f;
  float ltx=fmaxf(ax1,bx1), lty=fmaxf(ay1,by1);
  float rbx=fminf(ax2,bx2), rby=fminf(ay2,by2);
  float iw=fmaxf(rbx-ltx,0.0f), ih=fmaxf(rby-lty,0.0f);
  float inter=iw*ih;
  float aa=(ax2-ax1)*(ay2-ay1);
  return inter*frcp(aa+ab-inter+FEPS);
}

// One wave per (b, sc, g) task -> compact (npos, biou, npos cells).
// Additionally each block computes the dense z=0 focal sum over 1/10 of its
// (b,sc) obj plane -> exclusive ws slot (pure write; no init needed).
// Block 0 zeroes out[0] for k_pos's atomicAdds (next dispatch — race-free).
__global__ __launch_bounds__(256) void k_assign(
    const float* __restrict__ p0, const float* __restrict__ p1,
    const float* __restrict__ p2, const float* __restrict__ tg,
    int2* __restrict__ meta, int* __restrict__ cells,
    float* __restrict__ ws_focal, float* __restrict__ out)
{
  if (blockIdx.x == 0 && threadIdx.x == 0) out[0] = 0.0f;
  int lane = threadIdx.x & 63;
  int wv   = threadIdx.x >> 6;
  int task = (blockIdx.x<<2) + wv;      // 0..7679; 4 tasks/block, same (b,sc)
  int g  = task % NGT;
  int bs = task / NGT;
  int sc = bs % 3;
  int b  = bs / 3;

  const float* tp = tg + (b*NGT + g)*7;
  float cls = tp[0], cx = tp[1], cy = tp[2], w = tp[3], h = tp[4];
  float sz = fmaxf(w,h)*1280.0f;
  bool valid = (cls == 0.0f);
  if (sc==0)      valid = valid && (sz < 128.0f);
  else if (sc==1) valid = valid && (sz >= 48.0f) && (sz < 288.0f);
  else            valid = valid && (sz >= 128.0f);

  int W, HW; float s; const float* P;
  if (sc==0)      { W=160; HW=HW0; s=8.0f/1280.0f;  P=p0; }
  else if (sc==1) { W=80;  HW=HW1; s=16.0f/1280.0f; P=p1; }
  else            { W=40;  HW=HW2; s=32.0f/1280.0f; P=p2; }
  P += (size_t)b*7*HW;

  if (!valid){
    if (lane==0) meta[task] = make_int2(0,0);
  } else {
    float inv_s = 1280.0f/(float)((sc==0)?8:(sc==1)?16:32);
    float cxg = cx*inv_s, cyg = cy*inv_s;
    float bx1 = cx - w*0.5f, bx2 = cx + w*0.5f;
    float by1 = cy - h*0.5f, by2 = cy + h*0.5f;
    float ab  = (bx2-bx1)*(by2-by1);
    float bxl = bx1*inv_s, bxr = bx2*inv_s, byt = by1*inv_s, byb = by2*inv_s;

    // bounding rect of (in_center | in_box), +1 margin; exact predicates inside
    int x0 = max(0,   (int)floorf(fminf(cxg-2.5f, bxl)) - 1);
    int x1 = min(W-1, (int)floorf(fmaxf(cxg+2.5f, bxr)) + 1);
    int y0 = max(0,   (int)floorf(fminf(cyg-2.5f, byt)) - 1);
    int y1 = min(W-1, (int)floorf(fmaxf(cyg+2.5f, byb)) + 1);
    int rw = x1-x0+1, rh = y1-y0+1;
    int rn = rw*rh;

    unsigned long long t[10];
    #pragma unroll
    for (int j=0;j<10;++j) t[j]=SENT;
    int ncand = 0; float iousum = 0.0f;
    unsigned long long dmin = SENT;

    int rx = lane % rw, ry = lane / rw;
    int stepy = 64 / rw, stepx = 64 % rw;
    for (int r = lane; r < rn; r += 64){
      float gxf = (float)(x0+rx), gyf = (float)(y0+ry);
      int cell = (y0+ry)*W + (x0+rx);
      float q1 = P[HW+cell], q2 = P[2*HW+cell], q3 = P[3*HW+cell], q4 = P[4*HW+cell];
      float pcx = (fsigm(q1)+gxf)*s;
      float pcy = (fsigm(q2)+gyf)*s;
      float pw = __expf(fminf(fmaxf(q3,-5.0f),5.0f))*s;
      float ph = __expf(fminf(fmaxf(q4,-5.0f),5.0f))*s;
      float ax1 = pcx-pw*0.5f, ay1 = pcy-ph*0.5f, ax2 = pcx+pw*0.5f, ay2 = pcy+ph*0.5f;
      float ltx = fmaxf(ax1,bx1), lty = fmaxf(ay1,by1);
      float rbx = fminf(ax2,bx2), rby = fminf(ay2,by2);
      float iw = fmaxf(rbx-ltx,0.0f), ih = fmaxf(rby-lty,0.0f);
      float inter = iw*ih;
      float aa = (ax2-ax1)*(ay2-ay1);
      float iou = inter * frcp(aa+ab-inter+FEPS);
      bool ic = (fabsf(gxf-cxg)<2.5f) && (fabsf(gyf-cyg)<2.5f);
      bool ib = (gxf>=bxl)&&(gxf<bxr)&&(gyf>=byt)&&(gyf<byb);
      float dx = gxf-cxg, dy = gyf-cyg;
      float dist = dx*dx+dy*dy;
      unsigned long long dk = (((unsigned long long)__float_as_uint(dist))<<32)|(unsigned)cell;
      dmin = (dk<dmin)?dk:dmin;
      if (ic|ib){
        ncand += 1; iousum += iou;
        float q0 = P[cell];
        // monotone-equivalent cost key: cost = log[(1+e^-q0)/(iou+eps)^3];
        // the ratio itself preserves ascending order, so skip both logs.
        float ti = iou + FEPS;
        float ratio = (1.0f + __expf(-q0)) * frcp(ti*ti*ti);   // > 0, finite
        unsigned long long pk = (((unsigned long long)__float_as_uint(ratio))<<32)|(unsigned)cell;
        if (pk < t[9]){
          t[9] = pk;
          #pragma unroll
          for (int j=9;j>0;--j){ if (t[j]<t[j-1]){ unsigned long long tmp=t[j]; t[j]=t[j-1]; t[j-1]=tmp; } }
        }
      }
      rx += stepx; ry += stepy;
      if (rx >= rw){ rx -= rw; ry += 1; }
    }

    int NC = wredi(ncand);            // all lanes get the result (xor butterfly)
    float IS = wredf(iousum);
    dmin = wredmin64(dmin);

    int npos, cell0;
    if (NC==0){                        // fallback (never fires w/ this data)
      npos = 1; cell0 = (int)(unsigned)dmin;
      if (lane==0) cells[task*10] = cell0;
    } else {
      int ub = NC < 10 ? NC : 10;
      int v = (int)floorf(IS);
      v = v < 1 ? 1 : v;
      npos = v > ub ? ub : v;
      // exactly npos selection rounds over per-lane sorted lists (unique keys)
      int ptr = 0; cell0 = 0;
      for (int rd=0; rd<npos; ++rd){
        unsigned long long head = SENT;
        #pragma unroll
        for (int j=0;j<10;++j) head = (ptr==j)? t[j] : head;
        unsigned long long m = wredmin64(head);
        if (rd==0) cell0 = (int)(unsigned)m;
        if (lane==0) cells[task*10+rd] = (int)(unsigned)m;
        if (head==m && m!=SENT) ptr += 1;
      }
    }
    if (lane==0){
      float biou = iou_of_cell_f(P, HW, cell0, W, s, bx1, by1, bx2, by2, ab);
      meta[task] = make_int2(npos, __float_as_int(biou));
    }
  }

  // ---- dense z=0 focal over 1/10 of this block's (b,sc) obj plane ----
  float osum = 0.0f;
  {
    int chunk = blockIdx.x % 10;                  // tasks in block share bs
    int n4c = (HW/10) >> 2;                       // 640 / 160 / 40 float4
    const float4* Q4 = (const float4*)P + chunk*n4c;
    for (int i = threadIdx.x; i < n4c; i += 256){
      float4 x4 = Q4[i];
      osum += focal0(x4.x) + focal0(x4.y) + focal0(x4.z) + focal0(x4.w);
    }
  }
  osum = wredf(osum);
  __shared__ float redf[4];
  if (lane==0) redf[wv] = osum;
  __syncthreads();
  if (threadIdx.x==0) ws_focal[blockIdx.x] = redf[0]+redf[1]+redf[2]+redf[3];
}

// One block per (b, sc): sparse-only. Winner resolution over <=400 compact
// entries, focal correction + CIoU + foot at owner cells, combine with the
// dense focal partials from k_assign. One fire-and-forget atomicAdd(out).
__global__ __launch_bounds__(512) void k_pos(
    const float* __restrict__ p0, const float* __restrict__ p1,
    const float* __restrict__ p2, const float* __restrict__ tg,
    const int2* __restrict__ meta, const int* __restrict__ cells,
    const float* __restrict__ ws_focal, float* __restrict__ out)
{
  __shared__ int   s_pack[MAXE];   // (cell<<6)|g
  __shared__ float s_biou[MAXE];
  __shared__ int   s_cnt;
  __shared__ float red[4][8];

  int u = blockIdx.x;        // 0..191 == bs
  int b = u / 3, sc = u - b*3;
  int W, HW; float s; const float* P;
  if (sc==0)      { W=160; HW=HW0; s=8.0f/1280.0f;  P=p0; }
  else if (sc==1) { W=80;  HW=HW1; s=16.0f/1280.0f; P=p1; }
  else            { W=40;  HW=HW2; s=32.0f/1280.0f; P=p2; }
  P += (size_t)b*7*HW;

  if (threadIdx.x == 0) s_cnt = 0;
  __syncthreads();

  // compact valid (cell, g, biou) entries into LDS
  int tbase = u*NGT;
  if (threadIdx.x < NGT*10){
    int g = threadIdx.x / 10, sl = threadIdx.x - g*10;
    int2 m = meta[tbase + g];
    if (sl < m.x){
      int idx = atomicAdd(&s_cnt, 1);
      s_pack[idx] = (cells[(tbase+g)*10 + sl] << 6) | g;
      s_biou[idx] = __int_as_float(m.y);
    }
  }
  __syncthreads();
  int E = s_cnt;

  float osum = 0.0f, np = 0.0f, bsum = 0.0f, fsum = 0.0f;

  // dense focal partials from k_assign (10 exclusive slots for this bs)
  if (threadIdx.x < 10) osum = ws_focal[u*10 + threadIdx.x];

  // sparse: resolve winner (max g) and obj (max biou) per selected cell
  if (threadIdx.x < E){
    int myp = s_pack[threadIdx.x];
    int mycell = myp >> 6;
    int pm = myp; float bm = s_biou[threadIdx.x];
    for (int j = 0; j < E; ++j){
      int p = s_pack[j];
      if ((p>>6) == mycell){
        pm = max(pm, p);
        bm = fmaxf(bm, s_biou[j]);
      }
    }
    if (pm == myp){            // this entry owns the cell (max g, unique)
      np = 1.0f;
      int wg = myp & 63;
      float z = bm;
      int i = mycell;
      float x = P[i];
      osum += focalz(x, z) - focal0(x);    // correct the dense z=0 term
      const float* tpb = tg + (b*NGT + wg)*7;
      float cx=tpb[1], cy=tpb[2], w=tpb[3], h=tpb[4], fx=tpb[5], fy=tpb[6];
      int gyi = i / W;
      float gxf = (float)(i - gyi*W), gyf = (float)gyi;
      float pcx = (fsigm(P[HW+i])+gxf)*s;
      float pcy = (fsigm(P[2*HW+i])+gyf)*s;
      float pw = __expf(fminf(fmaxf(P[3*HW+i],-5.0f),5.0f))*s;
      float ph = __expf(fminf(fmaxf(P[4*HW+i],-5.0f),5.0f))*s;
      float tw = w + FEPS*s, th = h + FEPS*s;   // exp(log(w/s+eps))*s
      float px1=pcx-pw*0.5f, py1=pcy-ph*0.5f, px2=pcx+pw*0.5f, py2=pcy+ph*0.5f;
      float tx1=cx-tw*0.5f, ty1=cy-th*0.5f, tx2=cx+tw*0.5f, ty2=cy+th*0.5f;
      float iw = fmaxf(fminf(px2,tx2)-fmaxf(px1,tx1),0.0f);
      float ih = fmaxf(fminf(py2,ty2)-fmaxf(py1,ty1),0.0f);
      float inter = iw*ih;
      float uni = pw*ph + tw*th - inter + FEPS;
      float iou = inter/uni;
      float rho2 = (pcx-cx)*(pcx-cx)+(pcy-cy)*(pcy-cy);
      float cw = fmaxf(px2,tx2)-fminf(px1,tx1);
      float ch = fmaxf(py2,ty2)-fminf(py1,ty1);
      float c2 = cw*cw+ch*ch+FEPS;
      float da = atanf(tw/(th+FEPS)) - atanf(pw/(ph+FEPS));
      float v = (4.0f/(float)(M_PI*M_PI))*da*da;
      float alpha = v/(1.0f-iou+v+FEPS);
      float ciou = iou - rho2/c2 - alpha*v;
      bsum = 1.0f - ciou;
      float pf1 = fsigm(P[5*HW+i]);
      float pf2 = fsigm(P[6*HW+i]);
      float d1 = fabsf(pf1-fx), d2 = fabsf(pf2-fy);
      fsum = (d1<1.0f? 0.5f*d1*d1 : d1-0.5f) + (d2<1.0f? 0.5f*d2*d2 : d2-0.5f);
    }
  }

  // block reduction (8 waves)
  int wv = threadIdx.x >> 6, lane = threadIdx.x & 63;
  osum = wredf(osum); np = wredf(np); bsum = wredf(bsum); fsum = wredf(fsum);
  if (lane==0){ red[0][wv]=osum; red[1][wv]=np; red[2][wv]=bsum; red[3][wv]=fsum; }
  __syncthreads();
  if (threadIdx.x==0){
    float a0=0,a1=0,a2=0,a3=0;
    #pragma unroll
    for (int j=0;j<8;++j){ a0+=red[0][j]; a1+=red[1][j]; a2+=red[2][j]; a3+=red[3][j]; }
    float hw = (float)HW;
    float npz = fmaxf(a1, 1.0f);
    float c = (a0/hw + 5.0f*a2/npz + a3/npz) * (1.0f/64.0f);
    atomicAdd(out, c);       // fire-and-forget; order-nondet ~1e-6 << threshold
  }
}

extern "C" void kernel_launch(void* const* d_in, const int* in_sizes, int n_in,
                              void* d_out, int out_size, void* d_ws, size_t ws_size,
                              hipStream_t stream) {
  (void)in_sizes; (void)n_in; (void)out_size; (void)ws_size;
  const float* p0 = (const float*)d_in[0];
  const float* p1 = (const float*)d_in[1];
  const float* p2 = (const float*)d_in[2];
  const float* tg = (const float*)d_in[3];

  int2*  meta     = (int2*)d_ws;                                   // NTASK int2
  int*   cells    = (int*)((char*)d_ws + (size_t)NTASK*8);         // NTASK*10 int
  float* ws_focal = (float*)((char*)d_ws + (size_t)NTASK*48);      // NABLK floats
  float* out      = (float*)d_out;

  k_assign<<<NABLK, 256, 0, stream>>>(p0, p1, p2, tg, meta, cells, ws_focal, out);
  k_pos   <<<NBATCH*3, 512, 0, stream>>>(p0, p1, p2, tg, meta, cells, ws_focal, out);
}